// Round 18
// baseline (116.031 us; speedup 1.0000x reference)
//
#include <hip/hip_runtime.h>
#include <hip/hip_bf16.h>

#define N_ROWS 8192
#define D_DIM  256

// loss_i = log(sum_{j != i} exp(<x_i,y_j>/T)) - <x_i,y_i>/T ; out = mean_i loss_i
// fp8 e4m3 inputs (scale 64), PLAIN row-major; acc = 4096*<x,y> via MX-scaled
// MFMA 16x16x128 with unit E8M0 scales (exact fp8 dot); 1/4096 in constants.
static constexpr float kQuantScale = 64.0f;
static constexpr float kScaleAcc = 20.609929155556627f / 4096.0f;  // (1/T)*log2(e)/4096
static constexpr float kInvTAcc  = 14.285714285714286f / 4096.0f;  // (1/T)/4096

typedef float f32x4 __attribute__((ext_vector_type(4)));
typedef int   i32x4 __attribute__((ext_vector_type(4)));
typedef int   i32x8 __attribute__((ext_vector_type(8)));

// async 16B global->LDS: LDS dest = wave-uniform base + lane*16
__device__ __forceinline__ void gl_lds16(const void* g, void* l) {
  __builtin_amdgcn_global_load_lds(
      (const __attribute__((address_space(1))) void*)g,
      (__attribute__((address_space(3))) void*)l, 16, 0, 0);
}

// ---------------- fp32 -> fp8 e4m3 pre-convert (plain layout) + ws init --------
__global__ __launch_bounds__(256)
void cvt_fp8_kernel(const float* __restrict__ x, const float* __restrict__ y,
                    unsigned char* __restrict__ xq, unsigned char* __restrict__ yq,
                    float* __restrict__ rowsum, unsigned int* __restrict__ done) {
  if (blockIdx.x == 0) {
    for (int i = threadIdx.x; i < N_ROWS; i += 256) rowsum[i] = 0.f;
    if (threadIdx.x == 0) *done = 0u;
  }
  const int per_mat = N_ROWS * D_DIM / 8;  // 8 elements per thread
  int idx = blockIdx.x * blockDim.x + threadIdx.x;
  const float* src = x;
  unsigned char* dst = xq;
  int i = idx;
  if (idx >= per_mat) { src = y; dst = yq; i = idx - per_mat; }
  float4 a = ((const float4*)src)[2 * (size_t)i];
  float4 b = ((const float4*)src)[2 * (size_t)i + 1];
  int v0 = 0, v1 = 0;
  v0 = __builtin_amdgcn_cvt_pk_fp8_f32(a.x * kQuantScale, a.y * kQuantScale, v0, false);
  v0 = __builtin_amdgcn_cvt_pk_fp8_f32(a.z * kQuantScale, a.w * kQuantScale, v0, true);
  v1 = __builtin_amdgcn_cvt_pk_fp8_f32(b.x * kQuantScale, b.y * kQuantScale, v1, false);
  v1 = __builtin_amdgcn_cvt_pk_fp8_f32(b.z * kQuantScale, b.w * kQuantScale, v1, true);
  *(int2*)(dst + (size_t)i * 8) = make_int2(v0, v1);   // plain row-major
}

// ---------------- persistent GEMM(MX-fp8), producer/consumer waves -------------
// 256 blocks (1/CU), 576 threads = 9 waves. Waves 0..7: R17 compute geometry
// (wm 0..3, wn 0..1; wave tile 64x64; MX MFMA 16x16x128; psum in registers).
// Wave 8: PRODUCER — issues all global_load_lds staging (X 64 KB once, 8 Y
// tiles of 32 KB double-buffered) and publishes readiness through LDS
// acquire/release flags. NO __syncthreads in the round loop: compute waves
// spin on ready[], release buffers via consumed[] — phases of different waves
// skew and co-schedule (m114), and no wave ever drains the vmcnt FIFO.
// All acc/psum indices compile-time (R10); no per-block device fences (R4);
// single-fence ticket finalize (R12); register psum (R17).
__global__ __launch_bounds__(576, 1)
void infonce_gemm(const unsigned char* __restrict__ X,
                  const unsigned char* __restrict__ Y,
                  float* __restrict__ rowsum, float* __restrict__ diag,
                  unsigned int* __restrict__ done, float* __restrict__ out) {
  __shared__ unsigned char Xs[256 * 256];      // 64 KB, X-block full-K
  __shared__ unsigned char Ys[2][128 * 256];   // 2 x 32 KB, Y tile dbuf
  __shared__ int ready[2];                     // latest round staged per buffer
  __shared__ int consumed[2];                  // waves-finished count per buffer
  __shared__ unsigned int ticket_s;

  const int b  = blockIdx.x;        // 0..255
  const int bi = b >> 3;            // 0..31: X-row-block (256 rows)
  const int gj = b & 7;             // col-group: col-tile ct = gj*8 + tt

  const int t    = threadIdx.x;
  const int lane = t & 63;
  const int wave = t >> 6;        // 0..8
  const int wm   = wave >> 1;     // 0..3 (compute waves)
  const int wn   = wave & 1;      // 0..1
  const int quad = lane >> 4;     // 0..3
  const int l15  = lane & 15;

  if (t == 0) { ready[0] = -1; ready[1] = -1; consumed[0] = 0; consumed[1] = 0; }
  __syncthreads();   // the only barrier before the end of the block

  if (wave == 8) {
    // ================= PRODUCER =================
    const unsigned char* Xblk = X + (size_t)(bi * 256) * D_DIM;
    // X: 4096 slots of 16B, 64 instrs
    for (int it = 0; it < 64; ++it) {
      const int c0  = it * 64;
      const int s   = c0 + lane;
      const int row = s >> 4;
      const int cg  = (s & 15) ^ (row & 15);
      gl_lds16(Xblk + (size_t)row * D_DIM + cg * 16, &Xs[c0 * 16]);
    }
    // Y tile 0 into buffer 0
    {
      const unsigned char* Yblk = Y + (size_t)(gj * 8) * 128 * D_DIM;
      for (int it = 0; it < 32; ++it) {
        const int c0  = it * 64;
        const int s   = c0 + lane;
        const int row = s >> 4;
        const int cg  = (s & 15) ^ (row & 15);
        gl_lds16(Yblk + (size_t)row * D_DIM + cg * 16, &Ys[0][c0 * 16]);
      }
    }
    __builtin_amdgcn_s_waitcnt(0);   // X + Y0 landed in LDS
    __hip_atomic_store(&ready[0], 0, __ATOMIC_RELEASE, __HIP_MEMORY_SCOPE_WORKGROUP);
    // Y tiles 1..7
    for (int r = 1; r < 8; ++r) {
      const int bb = r & 1;
      if (r >= 2) {  // wait until round r-2 (same buffer) fully consumed
        const int need = 8 * (r >> 1);
        while (__hip_atomic_load(&consumed[bb], __ATOMIC_ACQUIRE,
                                 __HIP_MEMORY_SCOPE_WORKGROUP) < need)
          __builtin_amdgcn_s_sleep(2);
      }
      const unsigned char* Yblk = Y + (size_t)(gj * 8 + r) * 128 * D_DIM;
      for (int it = 0; it < 32; ++it) {
        const int c0  = it * 64;
        const int s   = c0 + lane;
        const int row = s >> 4;
        const int cg  = (s & 15) ^ (row & 15);
        gl_lds16(Yblk + (size_t)row * D_DIM + cg * 16, &Ys[bb][c0 * 16]);
      }
      __builtin_amdgcn_s_waitcnt(0);
      __hip_atomic_store(&ready[bb], r, __ATOMIC_RELEASE, __HIP_MEMORY_SCOPE_WORKGROUP);
    }
  } else {
    // ================= COMPUTE (waves 0..7) =================
    f32x4 acc[4][4];
#pragma unroll
    for (int a = 0; a < 4; ++a)
#pragma unroll
      for (int c = 0; c < 4; ++c) acc[a][c] = (f32x4){0.f, 0.f, 0.f, 0.f};
    float psum[4][4];
#pragma unroll
    for (int a = 0; a < 4; ++a)
#pragma unroll
      for (int c = 0; c < 4; ++c) psum[a][c] = 0.f;

    for (int tt = 0; tt < 8; ++tt) {
      const int p = tt & 1;
      while (__hip_atomic_load(&ready[p], __ATOMIC_ACQUIRE,
                               __HIP_MEMORY_SCOPE_WORKGROUP) < tt)
        __builtin_amdgcn_s_sleep(1);

      // 2 MX k-blocks of 128; per kb: 8 frag b128-pairs + 16 MFMA
#pragma unroll
      for (int kb = 0; kb < 2; ++kb) {
        i32x8 a8[4], b8[4];
#pragma unroll
        for (int mt = 0; mt < 4; ++mt) {
          const int row = wm * 64 + mt * 16 + l15;
          const int p0  = (kb * 8 + quad * 2 + 0) ^ (row & 15);
          const int p1  = (kb * 8 + quad * 2 + 1) ^ (row & 15);
          i32x4 lo = *(const i32x4*)(&Xs[row * 256 + p0 * 16]);
          i32x4 hi = *(const i32x4*)(&Xs[row * 256 + p1 * 16]);
          a8[mt] = __builtin_shufflevector(lo, hi, 0, 1, 2, 3, 4, 5, 6, 7);
        }
#pragma unroll
        for (int nt = 0; nt < 4; ++nt) {
          const int row = wn * 64 + nt * 16 + l15;
          const int p0  = (kb * 8 + quad * 2 + 0) ^ (row & 15);
          const int p1  = (kb * 8 + quad * 2 + 1) ^ (row & 15);
          i32x4 lo = *(const i32x4*)(&Ys[p][row * 256 + p0 * 16]);
          i32x4 hi = *(const i32x4*)(&Ys[p][row * 256 + p1 * 16]);
          b8[nt] = __builtin_shufflevector(lo, hi, 0, 1, 2, 3, 4, 5, 6, 7);
        }
#pragma unroll
        for (int mt = 0; mt < 4; ++mt)
#pragma unroll
          for (int nt = 0; nt < 4; ++nt)
            acc[mt][nt] = __builtin_amdgcn_mfma_scale_f32_16x16x128_f8f6f4(
                a8[mt], b8[nt], acc[mt][nt],
                0, 0, 0, 0x7F7F7F7F, 0, 0x7F7F7F7F);  // fp8/fp8, unit scales
      }

      // epilogue: exp + accumulate into registers (pure VALU, R17)
#pragma unroll
      for (int mt = 0; mt < 4; ++mt) {
#pragma unroll
        for (int rr = 0; rr < 4; ++rr) {
          float part = 0.f;
#pragma unroll
          for (int nt = 0; nt < 4; ++nt)
            part += __builtin_amdgcn_exp2f(acc[mt][nt][rr] * kScaleAcc);
          psum[mt][rr] += part;
        }
      }
      // diagonal (device-scope atomicExch; wave-uniform outer condition)
      {
        const int ct = gj * 8 + tt;
        const bool d0 = (ct == 2 * bi)     && (wm == wn);
        const bool d1 = (ct == 2 * bi + 1) && (wm == wn + 2);
        if (d0 || d1) {
          const int gi_base = bi * 256 + wm * 64;
#pragma unroll
          for (int nt = 0; nt < 4; ++nt)
#pragma unroll
            for (int rr = 0; rr < 4; ++rr)
              if (l15 == quad * 4 + rr)
                atomicExch(&diag[gi_base + nt * 16 + l15], acc[nt][nt][rr]);
        }
      }
#pragma unroll
      for (int a = 0; a < 4; ++a)
#pragma unroll
        for (int c = 0; c < 4; ++c) acc[a][c] = (f32x4){0.f, 0.f, 0.f, 0.f};

      if (lane == 0)  // release this buffer use (ds_reads already drained)
        __hip_atomic_fetch_add(&consumed[p], 1, __ATOMIC_RELEASE,
                               __HIP_MEMORY_SCOPE_WORKGROUP);
    }

    // one reduce + flush per block (16 shfl-chains + 16 atomics per wave)
    {
      const int gi_base = bi * 256 + wm * 64;
#pragma unroll
      for (int mt = 0; mt < 4; ++mt) {
#pragma unroll
        for (int rr = 0; rr < 4; ++rr) {
          float v = psum[mt][rr];
          v += __shfl_xor(v, 1);
          v += __shfl_xor(v, 2);
          v += __shfl_xor(v, 4);
          v += __shfl_xor(v, 8);
          if (l15 == 0)
            atomicAdd(&rowsum[gi_base + mt * 16 + quad * 4 + rr], v);
        }
      }
    }
  }

  // ---- last-block finalize (single fence — R12-validated) ----
  __syncthreads();                       // all waves done; block atomics issued
  if (t == 0) ticket_s = atomicAdd(done, 1u);
  __syncthreads();
  if (ticket_s == 255u) {
    __threadfence();                     // one acquire, one block only
    float local = 0.f;
    for (int i = t; i < N_ROWS; i += 576) {
      const float rs = atomicAdd(&rowsum[i], 0.0f);   // device-coherent read
      const float d  = atomicAdd(&diag[i], 0.0f);
      local += __logf(rs - __builtin_amdgcn_exp2f(d * kScaleAcc)) - d * kInvTAcc;
    }
    float* red = (float*)Xs;
    red[t] = local;
    __syncthreads();
    for (int s2 = 512; s2 > 0; s2 >>= 1) {
      if (t < s2 && t + s2 < 576) red[t] += red[t + s2];
      __syncthreads();
    }
    if (t == 0) out[0] = red[0] / (float)N_ROWS;
  }
}

extern "C" void kernel_launch(void* const* d_in, const int* in_sizes, int n_in,
                              void* d_out, int out_size, void* d_ws, size_t ws_size,
                              hipStream_t stream) {
  const float* x = (const float*)d_in[0];
  const float* y = (const float*)d_in[1];
  float* out = (float*)d_out;

  // ws layout: rowsum[N] f32 | diag[N] f32 | done u32(+pad) | xq | yq
  float* rowsum = (float*)d_ws;
  float* diag   = rowsum + N_ROWS;
  unsigned int* done = (unsigned int*)(diag + N_ROWS);
  unsigned char* xq = (unsigned char*)d_ws + 2 * N_ROWS * sizeof(float) + 16;
  unsigned char* yq = xq + (size_t)N_ROWS * D_DIM;

  int cvt_blocks = 2 * N_ROWS * D_DIM / 8 / 256;  // 2048
  cvt_fp8_kernel<<<cvt_blocks, 256, 0, stream>>>(x, y, xq, yq, rowsum, done);

  infonce_gemm<<<256, 576, 0, stream>>>(xq, yq, rowsum, diag, done, out);
}

// Round 19
// 107.242 us; speedup vs baseline: 1.0820x; 1.0820x over previous
//
#include <hip/hip_runtime.h>
#include <hip/hip_bf16.h>

#define N_ROWS 8192
#define D_DIM  256

// loss_i = log(sum_{j != i} exp(<x_i,y_j>/T)) - <x_i,y_i>/T ; out = mean_i loss_i
// fp8 e4m3 inputs (scale 64), PLAIN row-major; acc = 4096*<x,y> via MX-scaled
// MFMA 16x16x128 with unit E8M0 scales (exact fp8 dot); 1/4096 in constants.
static constexpr float kQuantScale = 64.0f;
static constexpr float kScaleAcc = 20.609929155556627f / 4096.0f;  // (1/T)*log2(e)/4096
static constexpr float kInvTAcc  = 14.285714285714286f / 4096.0f;  // (1/T)/4096

typedef float f32x4 __attribute__((ext_vector_type(4)));
typedef int   i32x4 __attribute__((ext_vector_type(4)));
typedef int   i32x8 __attribute__((ext_vector_type(8)));

// async 16B global->LDS: LDS dest = wave-uniform base + lane*16
__device__ __forceinline__ void gl_lds16(const void* g, void* l) {
  __builtin_amdgcn_global_load_lds(
      (const __attribute__((address_space(1))) void*)g,
      (__attribute__((address_space(3))) void*)l, 16, 0, 0);
}

// ---------------- fp32 -> fp8 e4m3 pre-convert (plain layout) + ws init --------
__global__ __launch_bounds__(256)
void cvt_fp8_kernel(const float* __restrict__ x, const float* __restrict__ y,
                    unsigned char* __restrict__ xq, unsigned char* __restrict__ yq,
                    float* __restrict__ rowsum, unsigned int* __restrict__ done) {
  if (blockIdx.x == 0) {
    for (int i = threadIdx.x; i < N_ROWS; i += 256) rowsum[i] = 0.f;
    if (threadIdx.x == 0) *done = 0u;
  }
  const int per_mat = N_ROWS * D_DIM / 8;  // 8 elements per thread
  int idx = blockIdx.x * blockDim.x + threadIdx.x;
  const float* src = x;
  unsigned char* dst = xq;
  int i = idx;
  if (idx >= per_mat) { src = y; dst = yq; i = idx - per_mat; }
  float4 a = ((const float4*)src)[2 * (size_t)i];
  float4 b = ((const float4*)src)[2 * (size_t)i + 1];
  int v0 = 0, v1 = 0;
  v0 = __builtin_amdgcn_cvt_pk_fp8_f32(a.x * kQuantScale, a.y * kQuantScale, v0, false);
  v0 = __builtin_amdgcn_cvt_pk_fp8_f32(a.z * kQuantScale, a.w * kQuantScale, v0, true);
  v1 = __builtin_amdgcn_cvt_pk_fp8_f32(b.x * kQuantScale, b.y * kQuantScale, v1, false);
  v1 = __builtin_amdgcn_cvt_pk_fp8_f32(b.z * kQuantScale, b.w * kQuantScale, v1, true);
  *(int2*)(dst + (size_t)i * 8) = make_int2(v0, v1);   // plain row-major
}

// ---------------- persistent fused GEMM(MX-fp8), 2 blocks/CU -------------------
// R19: 512 blocks x 256 threads (4 waves), LDS exactly 64 KB -> 2 co-resident
// blocks per CU. When one block drains its barrier, the other's waves compute
// (m114 co-scheduling) — overlap via the dispatcher, not hand-rolled flags
// (R18's single producer wave was issue-limited and regressed).
// Block: X-row-block bi2 (128 rows, full K, 32 KB staged once) x col-group gj
// (1024 cols = 16 Y tiles of 64 cols, 16 KB each, double-buffered 32 KB).
// Wave tile 64x32 = 4x2 MFMA tiles; MX MFMA 16x16x128 unit scales (R15);
// register psum (R17); XOR-16 swizzle both sides (R12); all indices
// compile-time (R10); no per-block device fences (R4); single-fence ticket
// finalize (R12).
__global__ __launch_bounds__(256, 2)
void infonce_gemm(const unsigned char* __restrict__ X,
                  const unsigned char* __restrict__ Y,
                  float* __restrict__ rowsum, float* __restrict__ diag,
                  unsigned int* __restrict__ done, float* __restrict__ out) {
  __shared__ unsigned char Xs[128 * 256];      // 32 KB, X-block full-K
  __shared__ unsigned char Ys[2][64 * 256];    // 2 x 16 KB, Y tile dbuf
  __shared__ unsigned int ticket_s;

  const int b   = blockIdx.x;       // 0..511
  const int bi2 = b >> 3;           // 0..63: X-row-block (128 rows)
  const int gj  = b & 7;            // col-group: col-tile ct = gj*16 + tt

  const int t    = threadIdx.x;
  const int lane = t & 63;
  const int wave = t >> 6;        // 0..3
  const int wm   = wave >> 1;     // 0..1  (64-row half)
  const int wn   = wave & 1;      // 0..1  (32-col half)
  const int quad = lane >> 4;     // 0..3
  const int l15  = lane & 15;

  const unsigned char* Xblk = X + (size_t)(bi2 * 128) * D_DIM;

  // ---- prologue: stage X (2048 slots of 16B, 8 per thread) ----
#pragma unroll
  for (int it = 0; it < 8; ++it) {
    const int c0  = (it * 4 + wave) * 64;
    const int s   = c0 + lane;
    const int row = s >> 4;                 // 0..127
    const int cg  = (s & 15) ^ (row & 15);  // inverse swizzle on global side
    gl_lds16(Xblk + (size_t)row * D_DIM + cg * 16, &Xs[c0 * 16]);
  }
  // stage Y tile 0 (1024 slots, 4 per thread) into buffer 0
  {
    const unsigned char* Yblk = Y + (size_t)(gj * 16) * 64 * D_DIM;
#pragma unroll
    for (int it = 0; it < 4; ++it) {
      const int c0  = (it * 4 + wave) * 64;
      const int s   = c0 + lane;
      const int row = s >> 4;                 // 0..63
      const int cg  = (s & 15) ^ (row & 15);
      gl_lds16(Yblk + (size_t)row * D_DIM + cg * 16, &Ys[0][c0 * 16]);
    }
  }

  f32x4 acc[4][2];
#pragma unroll
  for (int a = 0; a < 4; ++a)
#pragma unroll
    for (int c = 0; c < 2; ++c) acc[a][c] = (f32x4){0.f, 0.f, 0.f, 0.f};

  float psum[4][4];   // per-lane running row-sum partials
#pragma unroll
  for (int a = 0; a < 4; ++a)
#pragma unroll
    for (int c = 0; c < 4; ++c) psum[a][c] = 0.f;

  for (int tt = 0; tt < 16; ++tt) {
    const int p = tt & 1;

    __syncthreads();   // round tt staged (vmcnt drained by barrier)

    if (tt < 15) {     // stage Y tile tt+1 into the other buffer
      const unsigned char* Yblk = Y + (size_t)(gj * 16 + tt + 1) * 64 * D_DIM;
#pragma unroll
      for (int it = 0; it < 4; ++it) {
        const int c0  = (it * 4 + wave) * 64;
        const int s   = c0 + lane;
        const int row = s >> 4;
        const int cg  = (s & 15) ^ (row & 15);
        gl_lds16(Yblk + (size_t)row * D_DIM + cg * 16, &Ys[p ^ 1][c0 * 16]);
      }
    }

    // full-K compute: 2 MX k-blocks of 128; per kb: 6 frag b128-pairs + 8 MFMA
#pragma unroll
    for (int kb = 0; kb < 2; ++kb) {
      i32x8 a8[4], b8[2];
#pragma unroll
      for (int mt = 0; mt < 4; ++mt) {
        const int row = wm * 64 + mt * 16 + l15;
        const int p0  = (kb * 8 + quad * 2 + 0) ^ (row & 15);
        const int p1  = (kb * 8 + quad * 2 + 1) ^ (row & 15);
        i32x4 lo = *(const i32x4*)(&Xs[row * 256 + p0 * 16]);
        i32x4 hi = *(const i32x4*)(&Xs[row * 256 + p1 * 16]);
        a8[mt] = __builtin_shufflevector(lo, hi, 0, 1, 2, 3, 4, 5, 6, 7);
      }
#pragma unroll
      for (int nt = 0; nt < 2; ++nt) {
        const int row = wn * 32 + nt * 16 + l15;
        const int p0  = (kb * 8 + quad * 2 + 0) ^ (row & 15);
        const int p1  = (kb * 8 + quad * 2 + 1) ^ (row & 15);
        i32x4 lo = *(const i32x4*)(&Ys[p][row * 256 + p0 * 16]);
        i32x4 hi = *(const i32x4*)(&Ys[p][row * 256 + p1 * 16]);
        b8[nt] = __builtin_shufflevector(lo, hi, 0, 1, 2, 3, 4, 5, 6, 7);
      }
#pragma unroll
      for (int mt = 0; mt < 4; ++mt)
#pragma unroll
        for (int nt = 0; nt < 2; ++nt)
          acc[mt][nt] = __builtin_amdgcn_mfma_scale_f32_16x16x128_f8f6f4(
              a8[mt], b8[nt], acc[mt][nt],
              0, 0,                    // cbsz=fp8 e4m3, blgp=fp8 e4m3
              0, 0x7F7F7F7F,           // A scales = 1.0 (E8M0 127)
              0, 0x7F7F7F7F);          // B scales = 1.0
    }

    // ---- epilogue: exp + accumulate into registers (pure VALU, R17) ----
#pragma unroll
    for (int mt = 0; mt < 4; ++mt) {
#pragma unroll
      for (int rr = 0; rr < 4; ++rr) {
        float part = 0.f;
#pragma unroll
        for (int nt = 0; nt < 2; ++nt)
          part += __builtin_amdgcn_exp2f(acc[mt][nt][rr] * kScaleAcc);
        psum[mt][rr] += part;
      }
    }
    // diagonal: 64-col tile ct = gj*16+tt overlaps the block's rows iff
    // ct==2*bi2 (row offset 0 -> wm==0) or ct==2*bi2+1 (offset 64 -> wm==1).
    // In-wave: row subtile mt must equal wn*2 + nt — branch on wn so every
    // acc index is compile-time (R10 lesson).
    {
      const int ct = gj * 16 + tt;
      const bool dd = (ct == 2 * bi2 && wm == 0) || (ct == 2 * bi2 + 1 && wm == 1);
      if (dd) {
        const int gi_base = bi2 * 128 + wm * 64;
        if (wn == 0) {
#pragma unroll
          for (int nt = 0; nt < 2; ++nt)
#pragma unroll
            for (int rr = 0; rr < 4; ++rr)
              if (l15 == quad * 4 + rr)
                atomicExch(&diag[gi_base + nt * 16 + l15], acc[nt][nt][rr]);
        } else {
#pragma unroll
          for (int nt = 0; nt < 2; ++nt)
#pragma unroll
            for (int rr = 0; rr < 4; ++rr)
              if (l15 == quad * 4 + rr)
                atomicExch(&diag[gi_base + (2 + nt) * 16 + l15], acc[2 + nt][nt][rr]);
        }
      }
    }
#pragma unroll
    for (int a = 0; a < 4; ++a)
#pragma unroll
      for (int c = 0; c < 2; ++c) acc[a][c] = (f32x4){0.f, 0.f, 0.f, 0.f};
  }

  // ---- one reduce + flush per block (16 shfl-chains + 16 atomics per wave) ----
  {
    const int gi_base = bi2 * 128 + wm * 64;
#pragma unroll
    for (int mt = 0; mt < 4; ++mt) {
#pragma unroll
      for (int rr = 0; rr < 4; ++rr) {
        float v = psum[mt][rr];
        v += __shfl_xor(v, 1);
        v += __shfl_xor(v, 2);
        v += __shfl_xor(v, 4);
        v += __shfl_xor(v, 8);
        if (l15 == 0)
          atomicAdd(&rowsum[gi_base + mt * 16 + quad * 4 + rr], v);
      }
    }
  }

  // ---- last-block finalize (single fence — R12-validated) ----
  __syncthreads();                       // drains this block's atomics (vmcnt)
  if (t == 0) ticket_s = atomicAdd(done, 1u);
  __syncthreads();
  if (ticket_s == 511u) {
    __threadfence();                     // one acquire, one block only
    float local = 0.f;
    for (int i = t; i < N_ROWS; i += 256) {
      const float rs = atomicAdd(&rowsum[i], 0.0f);   // device-coherent read
      const float d  = atomicAdd(&diag[i], 0.0f);
      local += __logf(rs - __builtin_amdgcn_exp2f(d * kScaleAcc)) - d * kInvTAcc;
    }
    float* red = (float*)Xs;
    red[t] = local;
    __syncthreads();
    for (int s2 = 128; s2 > 0; s2 >>= 1) {
      if (t < s2) red[t] += red[t + s2];
      __syncthreads();
    }
    if (t == 0) out[0] = red[0] / (float)N_ROWS;
  }
}

extern "C" void kernel_launch(void* const* d_in, const int* in_sizes, int n_in,
                              void* d_out, int out_size, void* d_ws, size_t ws_size,
                              hipStream_t stream) {
  const float* x = (const float*)d_in[0];
  const float* y = (const float*)d_in[1];
  float* out = (float*)d_out;

  // ws layout: rowsum[N] f32 | diag[N] f32 | done u32(+pad) | xq | yq
  float* rowsum = (float*)d_ws;
  float* diag   = rowsum + N_ROWS;
  unsigned int* done = (unsigned int*)(diag + N_ROWS);
  unsigned char* xq = (unsigned char*)d_ws + 2 * N_ROWS * sizeof(float) + 16;
  unsigned char* yq = xq + (size_t)N_ROWS * D_DIM;

  int cvt_blocks = 2 * N_ROWS * D_DIM / 8 / 256;  // 2048
  cvt_fp8_kernel<<<cvt_blocks, 256, 0, stream>>>(x, y, xq, yq, rowsum, done);

  infonce_gemm<<<512, 256, 0, stream>>>(xq, yq, rowsum, diag, done, out);
}